// Round 1
// baseline (231.101 us; speedup 1.0000x reference)
//
#include <hip/hip_runtime.h>
#include <hip/hip_bf16.h>
#include <math.h>

typedef __attribute__((ext_vector_type(8))) __bf16 bf16x8;
typedef __attribute__((ext_vector_type(4))) __bf16 bf16x4;
typedef __attribute__((ext_vector_type(4))) float f32x4;

#define B_ 4
#define T_ 2048
#define C_ 1024
#define H_ 16
#define D_ 64
#define M_TOT (B_*T_)

static __device__ __forceinline__ f32x4 mfma_bf16(bf16x8 a, bf16x8 b, f32x4 c) {
  return __builtin_amdgcn_mfma_f32_16x16x32_bf16(a, b, c, 0, 0, 0);
}

static __device__ __forceinline__ void gload_lds16(const void* g, void* l) {
  __builtin_amdgcn_global_load_lds((const __attribute__((address_space(1))) void*)g,
                                   (__attribute__((address_space(3))) void*)l, 16, 0, 0);
}

// ---------------- converts ----------------

__global__ void f32_to_bf16_k(const float* __restrict__ in, __bf16* __restrict__ out, int n4) {
  int i = blockIdx.x * blockDim.x + threadIdx.x;
  if (i < n4) {
    float4 v = ((const float4*)in)[i];
    bf16x4 o = { (__bf16)v.x, (__bf16)v.y, (__bf16)v.z, (__bf16)v.w };
    *(bf16x4*)(out + (size_t)i*4) = o;
  }
}

// out[n][k] = in[k][n], out bf16 (N x K), in fp32 (K x N)
__global__ void transpose_to_bf16(const float* __restrict__ in, __bf16* __restrict__ out, int K, int N) {
  __shared__ float tile[32][33];
  int n0 = blockIdx.x * 32, k0 = blockIdx.y * 32;
  int tx = threadIdx.x & 31, ty = threadIdx.x >> 5;
  #pragma unroll
  for (int r = ty; r < 32; r += 8) tile[r][tx] = in[(size_t)(k0 + r)*N + n0 + tx];
  __syncthreads();
  #pragma unroll
  for (int r = ty; r < 32; r += 8) out[(size_t)(n0 + r)*K + k0 + tx] = (__bf16)tile[tx][r];
}

__global__ void rope_tables_k(float* __restrict__ cosT, float* __restrict__ sinT) {
  int idx = blockIdx.x * 256 + threadIdx.x;   // T_*32 total
  int t = idx >> 5, d = idx & 31;
  float inv = powf(10000.0f, -((float)(2*d)) / 64.0f);
  float ang = (float)t * inv;
  cosT[idx] = cosf(ang);
  sinT[idx] = sinf(ang);
}

// V [bh][t][d] -> Vt [bh][d][t]
__global__ void __launch_bounds__(256)
vtrans_k(const __bf16* __restrict__ v, __bf16* __restrict__ vt) {
  __shared__ __bf16 tile[64][72];
  const int tid = threadIdx.x;
  const int bh = blockIdx.y;
  const int t0 = blockIdx.x * 64;
  const __bf16* src = v + ((size_t)bh*T_ + t0)*D_;
  #pragma unroll
  for (int c = 0; c < 2; ++c) {
    int idx = tid + c*256;
    int row = idx >> 3, col8 = (idx & 7) * 8;
    *(bf16x8*)&tile[row][col8] = *(const bf16x8*)(src + row*D_ + col8);
  }
  __syncthreads();
  __bf16* dst = vt + (size_t)bh*D_*T_ + t0;
  #pragma unroll
  for (int c = 0; c < 2; ++c) {
    int idx = tid + c*256;
    int d = idx >> 3, t8 = (idx & 7) * 8;
    bf16x8 ov;
    #pragma unroll
    for (int j = 0; j < 8; ++j) ov[j] = tile[t8 + j][d];
    *(bf16x8*)(dst + (size_t)d*T_ + t8) = ov;
  }
}

// ---------------- QKV GEMM: 256x256 tile, BK=64, 8 waves, dbuf, 1-barrier/K-tile ----
#define GBK 64

__global__ void __launch_bounds__(512, 2)
gemm256_qkv(const __bf16* __restrict__ A, const __bf16* __restrict__ Bt,
            __bf16* __restrict__ qout, __bf16* __restrict__ kout, __bf16* __restrict__ vout,
            const float* __restrict__ cosT, const float* __restrict__ sinT)
{
  __shared__ __attribute__((aligned(16))) __bf16 lA[2][256*GBK];  // 32 KB each
  __shared__ __attribute__((aligned(16))) __bf16 lB[2][256*GBK];
  const int tid = threadIdx.x;
  const int lane = tid & 63, wave = tid >> 6;
  const int wr = wave >> 2, wc = wave & 3;       // 2 x 4 wave grid
  const int l15 = lane & 15, lhi = lane >> 4;

  const int id = blockIdx.x;                     // 384 blocks (384 % 8 == 0)
  const int n8 = gridDim.x >> 3;
  const int swz = (id & 7) * n8 + (id >> 3);
  const int row0 = (swz & 31) * 256;             // M/256 = 32
  const int col0 = (swz >> 5) * 256;             // N/256 = 12

  f32x4 acc[8][4] = {};

  const size_t lda = 1024 * 2;                   // K bytes per row
  const char* Abase = (const char*)A + (size_t)row0 * lda;
  const char* Bbase = (const char*)Bt + (size_t)col0 * lda;

  auto STAGE = [&](int kt, int s) {
    #pragma unroll
    for (int c = 0; c < 4; ++c) {
      const int L = tid*16 + c*8192;
      const int row = L >> 7, colb = L & 127;
      const int sb = colb ^ ((row & 7) << 4);    // inverse swizzle on global source
      gload_lds16(Abase + (size_t)row*lda + kt*128 + sb, (char*)lA[s] + L);
      gload_lds16(Bbase + (size_t)row*lda + kt*128 + sb, (char*)lB[s] + L);
    }
  };

  STAGE(0, 0);
  asm volatile("s_waitcnt vmcnt(0)" ::: "memory");
  __syncthreads();

  for (int kt = 0; kt < 16; ++kt) {
    const int cur = kt & 1;
    if (kt < 15) STAGE(kt + 1, cur ^ 1);

    // B fragments: read once per K-tile (4 n-frags x 2 k-steps)
    bf16x8 bfr[4][2];
    #pragma unroll
    for (int n = 0; n < 4; ++n) {
      const int row = wc*64 + n*16 + l15;
      const int sw = (row & 7) << 4;
      #pragma unroll
      for (int ks = 0; ks < 2; ++ks)
        bfr[n][ks] = *(const bf16x8*)((const char*)lB[cur] + row*128 + ((ks*64 + lhi*16) ^ sw));
    }
    // 4 phases: 2 m-rows each, 16 MFMA per phase
    #pragma unroll
    for (int mp = 0; mp < 4; ++mp) {
      bf16x8 af[2][2];
      #pragma unroll
      for (int mm = 0; mm < 2; ++mm) {
        const int row = wr*128 + (mp*2 + mm)*16 + l15;
        const int sw = (row & 7) << 4;
        #pragma unroll
        for (int ks = 0; ks < 2; ++ks)
          af[mm][ks] = *(const bf16x8*)((const char*)lA[cur] + row*128 + ((ks*64 + lhi*16) ^ sw));
      }
      __builtin_amdgcn_s_setprio(1);
      #pragma unroll
      for (int mm = 0; mm < 2; ++mm)
        #pragma unroll
        for (int n = 0; n < 4; ++n)
          #pragma unroll
          for (int ks = 0; ks < 2; ++ks)
            acc[mp*2 + mm][n] = mfma_bf16(af[mm][ks], bfr[n][ks], acc[mp*2 + mm][n]);
      __builtin_amdgcn_s_setprio(0);
    }

    asm volatile("s_waitcnt vmcnt(0)" ::: "memory");
    __syncthreads();
  }

  // epilogue: RoPE on q,k; scatter to (B,H,T,D); q pre-scaled by 0.125*log2e
  const int slot = (col0 >> 6) + wc;
  const int which = slot >> 4;
  const int h = slot & 15;
  const float fsc = (which == 0) ? 0.18033688011112042f : 1.0f;
  #pragma unroll
  for (int m = 0; m < 8; ++m) {
    #pragma unroll
    for (int r = 0; r < 4; ++r) {
      const int grow = row0 + wr*128 + m*16 + lhi*4 + r;
      const int b = grow >> 11, t = grow & 2047;
      const size_t obase = ((size_t)(b*H_ + h)*T_ + t)*D_;
      if (which == 2) {
        #pragma unroll
        for (int n = 0; n < 4; ++n)
          vout[obase + n*16 + l15] = (__bf16)acc[m][n][r];
      } else {
        __bf16* dst = (which == 0) ? qout : kout;
        #pragma unroll
        for (int n = 0; n < 2; ++n) {
          const int d1 = n*16 + l15;            // [0,32)
          const float c = cosT[t*32 + d1];
          const float s = sinT[t*32 + d1];
          const float x1 = acc[m][n][r];
          const float x2 = acc[m][n+2][r];
          dst[obase + d1]      = (__bf16)((x1*c - x2*s) * fsc);
          dst[obase + d1 + 32] = (__bf16)((x1*s + x2*c) * fsc);
        }
      }
    }
  }
}

// ---------------- out-proj GEMM (m97 structure: 128x128 tile, BK=64, 4 waves) -------
#define BM 128
#define BN 128
#define BK 64

__global__ void __launch_bounds__(256)
gemm_out(const __bf16* __restrict__ A, const __bf16* __restrict__ Bt, int K,
         float* __restrict__ fout, const float* __restrict__ bias)
{
  __shared__ __bf16 lA[BM*BK];
  __shared__ __bf16 lB[BN*BK];
  const int tid = threadIdx.x;
  const int lane = tid & 63, wave = tid >> 6;
  const int wr = wave >> 1, wc = wave & 1;
  const int l15 = lane & 15, lhi = lane >> 4;

  const int id = blockIdx.x;
  const int n8 = gridDim.x >> 3;
  const int swz = (id & 7) * n8 + (id >> 3);
  const int row0 = (swz & 63) * BM;
  const int col0 = (swz >> 6) * BN;

  f32x4 acc[4][4] = {};

  const int stago = wave*1024 + lane*16;
  const size_t arow0 = (size_t)row0 * (size_t)(K*2);
  const size_t brow0 = (size_t)col0 * (size_t)(K*2);

  for (int k0 = 0; k0 < K; k0 += BK) {
    #pragma unroll
    for (int r = 0; r < 4; ++r) {
      int ob = stago + r*4096;
      int row = ob >> 7;
      int colb = ob & 127;
      gload_lds16((const char*)A + arow0 + (size_t)row*(size_t)(K*2) + (size_t)(k0*2 + colb),
                  (char*)lA + ob);
      gload_lds16((const char*)Bt + brow0 + (size_t)row*(size_t)(K*2) + (size_t)(k0*2 + colb),
                  (char*)lB + ob);
    }
    __syncthreads();
    #pragma unroll
    for (int kk = 0; kk < BK; kk += 32) {
      bf16x8 af[4], bfr[4];
      #pragma unroll
      for (int m = 0; m < 4; ++m)
        af[m] = *(const bf16x8*)&lA[(wr*64 + m*16 + l15)*BK + kk + lhi*8];
      #pragma unroll
      for (int n = 0; n < 4; ++n)
        bfr[n] = *(const bf16x8*)&lB[(wc*64 + n*16 + l15)*BK + kk + lhi*8];
      #pragma unroll
      for (int m = 0; m < 4; ++m)
        #pragma unroll
        for (int n = 0; n < 4; ++n)
          acc[m][n] = mfma_bf16(af[m], bfr[n], acc[m][n]);
    }
    __syncthreads();
  }

  #pragma unroll
  for (int m = 0; m < 4; ++m) {
    #pragma unroll
    for (int r = 0; r < 4; ++r) {
      const int grow = row0 + wr*64 + m*16 + lhi*4 + r;
      #pragma unroll
      for (int n = 0; n < 4; ++n) {
        const int gcol = col0 + wc*64 + n*16 + l15;
        fout[(size_t)grow*1024 + gcol] = acc[m][n][r] + bias[gcol];
      }
    }
  }
}

// ---------------- flash attention: 1024 blocks (one q-tile each, heavy-first LPT),
// double-buffered K/V with prefetch-before-compute (T3 2-phase template),
// proven softmax/P-LDS path unchanged. LDS 48 KB -> 3 blocks/CU resident.
#define THR_LOG2 8.0f

__global__ void __launch_bounds__(256)
attn_kernel(const __bf16* __restrict__ q, const __bf16* __restrict__ k,
            const __bf16* __restrict__ vt, const int* __restrict__ amask,
            __bf16* __restrict__ aout)
{
  __shared__ __attribute__((aligned(16))) __bf16 lK[2][64*64];   // 16 KB
  __shared__ __attribute__((aligned(16))) __bf16 lVt[2][64*64];  // 16 KB
  __shared__ __attribute__((aligned(16))) __bf16 lP[4][32*64];   // 16 KB
  const int tid = threadIdx.x;
  const int lane = tid & 63, wave = tid >> 6;
  const int l15 = lane & 15, lhi = lane >> 4;

  // heavy q-tiles first: blockIdx 0..63 -> qblock 15 (nkb=32), ... LPT balance
  const int qblock = 15 - (blockIdx.x >> 6);
  const int bh = blockIdx.x & 63;

  const int b = bh >> 4, h = bh & 15;
  const size_t kvbase = (size_t)bh * T_ * D_;
  const char* kbase  = (const char*)(k + kvbase);
  const char* vtbase = (const char*)(vt + kvbase);
  char* lPw = (char*)lP[wave];

  const int q0w = qblock*128 + wave*32;

  bf16x8 aq[2][2];
  #pragma unroll
  for (int m = 0; m < 2; ++m)
    #pragma unroll
    for (int ks = 0; ks < 2; ++ks)
      aq[m][ks] = *(const bf16x8*)(q + kvbase + (size_t)(q0w + m*16 + l15)*D_ + ks*32 + lhi*8);

  f32x4 acc_o[2][4] = {};
  f32x4 acc_l[2] = {};
  float m_w = -3e37f;

  const int nkb = qblock*2 + 2;

  auto STAGE = [&](int kb, int s) {
    #pragma unroll
    for (int c = 0; c < 2; ++c) {
      const int L = tid*16 + c*4096;
      const int row = L >> 7;
      const int sb  = (L & 127) ^ ((row & 7) << 4);
      gload_lds16(kbase  + (size_t)(kb*64 + row)*128 + sb, (char*)lK[s] + L);
      gload_lds16(vtbase + (size_t)row*(T_*2) + (size_t)kb*128 + sb, (char*)lVt[s] + L);
    }
  };

  STAGE(0, 0);
  asm volatile("s_waitcnt vmcnt(0)" ::: "memory");
  __syncthreads();

  for (int kb = 0; kb < nkb; ++kb) {
    const int cur = kb & 1;
    if (kb + 1 < nkb) STAGE(kb + 1, cur ^ 1);   // prefetch in flight during compute

    if (kb*64 <= q0w + 31) {
      const char* lKc = (const char*)lK[cur];
      const char* lVc = (const char*)lVt[cur];

      f32x4 sc[2][4] = {};
      __builtin_amdgcn_s_setprio(1);
      #pragma unroll
      for (int n = 0; n < 4; ++n) {
        const int row = n*16 + l15;
        const int sw = (row & 7) << 4;
        #pragma unroll
        for (int ks = 0; ks < 2; ++ks) {
          bf16x8 bk = *(const bf16x8*)(lKc + row*128 + ((ks*64 + lhi*16) ^ sw));
          #pragma unroll
          for (int m = 0; m < 2; ++m)
            sc[m][n] = mfma_bf16(aq[m][ks], bk, sc[m][n]);
        }
      }
      __builtin_amdgcn_s_setprio(0);

      if (kb*64 + 63 > q0w) {
        #pragma unroll
        for (int m = 0; m < 2; ++m)
          #pragma unroll
          for (int r = 0; r < 4; ++r) {
            const int tq = q0w + m*16 + lhi*4 + r;
            #pragma unroll
            for (int n = 0; n < 4; ++n)
              if (kb*64 + n*16 + l15 > tq) sc[m][n][r] = -3e37f;
          }
      }

      f32x4 vm = sc[0][0];
      #pragma unroll
      for (int m = 0; m < 2; ++m)
        #pragma unroll
        for (int n = 0; n < 4; ++n) {
          if (m == 0 && n == 0) continue;
          #pragma unroll
          for (int r = 0; r < 4; ++r) vm[r] = fmaxf(vm[r], sc[m][n][r]);
        }
      float tmax = fmaxf(fmaxf(vm[0], vm[1]), fmaxf(vm[2], vm[3]));
      #pragma unroll
      for (int off = 1; off < 64; off <<= 1)
        tmax = fmaxf(tmax, __shfl_xor(tmax, off));

      if (tmax > m_w + THR_LOG2) {
        const float corr = __builtin_amdgcn_exp2f(m_w - tmax);
        #pragma unroll
        for (int m = 0; m < 2; ++m) {
          #pragma unroll
          for (int c = 0; c < 4; ++c) acc_o[m][c] *= corr;
          acc_l[m] *= corr;
        }
        m_w = tmax;
      }

      float mk[4];
      #pragma unroll
      for (int n = 0; n < 4; ++n)
        mk[n] = (amask[b*T_ + kb*64 + n*16 + l15] != 0) ? m_w : 3e37f;

      #pragma unroll
      for (int m = 0; m < 2; ++m)
        #pragma unroll
        for (int r = 0; r < 4; ++r) {
          const int row = m*16 + lhi*4 + r;
          const int sw = (row & 7) << 4;
          #pragma unroll
          for (int n = 0; n < 4; ++n) {
            const float p = __builtin_amdgcn_exp2f(sc[m][n][r] - mk[n]);
            *(__bf16*)(lPw + row*128 + ((((n*16 + l15)*2)) ^ sw)) = (__bf16)p;
          }
        }

      bf16x8 pa[2][2];
      #pragma unroll
      for (int m = 0; m < 2; ++m) {
        const int row = m*16 + l15;
        const int sw = (row & 7) << 4;
        #pragma unroll
        for (int ks = 0; ks < 2; ++ks)
          pa[m][ks] = *(const bf16x8*)(lPw + row*128 + ((ks*64 + lhi*16) ^ sw));
      }

      __builtin_amdgcn_s_setprio(1);
      const __bf16 one = (__bf16)1.0f;
      const bf16x8 vone = {one, one, one, one, one, one, one, one};
      #pragma unroll
      for (int m = 0; m < 2; ++m)
        #pragma unroll
        for (int ks = 0; ks < 2; ++ks)
          acc_l[m] = mfma_bf16(pa[m][ks], vone, acc_l[m]);

      #pragma unroll
      for (int c = 0; c < 4; ++c) {
        const int row = c*16 + l15;
        const int sw = (row & 7) << 4;
        #pragma unroll
        for (int ks = 0; ks < 2; ++ks) {
          bf16x8 bv = *(const bf16x8*)(lVc + row*128 + ((ks*64 + lhi*16) ^ sw));
          #pragma unroll
          for (int m = 0; m < 2; ++m)
            acc_o[m][c] = mfma_bf16(pa[m][ks], bv, acc_o[m][c]);
        }
      }
      __builtin_amdgcn_s_setprio(0);
    }

    // drain own prefetch loads, then barrier: buf[cur^1] complete for next iter,
    // and all reads of buf[cur] are done before anyone overwrites it.
    asm volatile("s_waitcnt vmcnt(0)" ::: "memory");
    __syncthreads();
  }

  #pragma unroll
  for (int m = 0; m < 2; ++m)
    #pragma unroll
    for (int r = 0; r < 4; ++r) {
      const int tq = q0w + m*16 + lhi*4 + r;
      const float invl = 1.0f / acc_l[m][r];
      const size_t obase = ((size_t)b*T_ + tq)*C_ + h*D_;
      #pragma unroll
      for (int c = 0; c < 4; ++c)
        aout[obase + c*16 + l15] = (__bf16)(acc_o[m][c][r] * invl);
    }
}

// ---------------- launch ----------------

extern "C" void kernel_launch(void* const* d_in, const int* in_sizes, int n_in,
                              void* d_out, int out_size, void* d_ws, size_t ws_size,
                              hipStream_t stream)
{
  const float* x     = (const float*)d_in[0];
  const int*   amask = (const int*)d_in[1];
  const float* Wqkv  = (const float*)d_in[2];
  const float* Wout  = (const float*)d_in[3];
  const float* bout  = (const float*)d_in[4];
  float* out = (float*)d_out;

  char* w = (char*)d_ws;
  __bf16* xb    = (__bf16*)w;  w += (size_t)M_TOT*C_*2;       // 16 MB (reused as vtb after QKV GEMM)
  __bf16* wqkvT = (__bf16*)w;  w += (size_t)3072*1024*2;      // 6 MB
  __bf16* woutT = (__bf16*)w;  w += (size_t)1024*1024*2;      // 2 MB
  __bf16* qb    = (__bf16*)w;  w += (size_t)B_*H_*T_*D_*2;    // 16 MB
  __bf16* kb    = (__bf16*)w;  w += (size_t)B_*H_*T_*D_*2;    // 16 MB
  __bf16* vb    = (__bf16*)w;  w += (size_t)B_*H_*T_*D_*2;    // 16 MB
  __bf16* aob   = (__bf16*)w;  w += (size_t)M_TOT*C_*2;       // 16 MB
  float*  cosT  = (float*)w;   w += (size_t)T_*32*4;
  float*  sinT  = (float*)w;   w += (size_t)T_*32*4;
  __bf16* vtb   = xb;   // xb dead after QKV GEMM; alias for V^T

  f32_to_bf16_k<<<(M_TOT*C_/4 + 255)/256, 256, 0, stream>>>(x, xb, M_TOT*C_/4);
  transpose_to_bf16<<<dim3(96, 32), 256, 0, stream>>>(Wqkv, wqkvT, 1024, 3072);
  transpose_to_bf16<<<dim3(32, 32), 256, 0, stream>>>(Wout, woutT, 1024, 1024);
  rope_tables_k<<<(T_*32)/256, 256, 0, stream>>>(cosT, sinT);

  gemm256_qkv<<<dim3(384), 512, 0, stream>>>(xb, wqkvT, qb, kb, vb, cosT, sinT);

  vtrans_k<<<dim3(T_/64, B_*H_), 256, 0, stream>>>(vb, vtb);

  attn_kernel<<<dim3(1024), 256, 0, stream>>>(qb, kb, vtb, amask, aob);

  gemm_out<<<dim3(64*8), 256, 0, stream>>>(
      aob, woutT, 1024, out, bout);
}